// Round 9
// baseline (266.361 us; speedup 1.0000x reference)
//
#include <hip/hip_runtime.h>
#include <hip/hip_bf16.h>

#define TDIM 2048
#define NDIM 2048
#define BHN  8
#define LD   2048

typedef __attribute__((ext_vector_type(8))) short bf16x8;
typedef __attribute__((ext_vector_type(4))) float f32x4;
typedef unsigned short us;

static __device__ __forceinline__ us f2bf(float x) {
  union { __hip_bfloat16 h; us u; } cv;
  cv.h = __float2bfloat16(x);
  return cv.u;
}

// ---------------- RoPE core (one bf16x8 unit, flat index over heads) ----------------
static __device__ __forceinline__ void rope_unit(const float* __restrict__ Q,
                                                 us* __restrict__ QR, long idx) {
  long base = idx * 8;
  int n = (int)(base & (NDIM - 1));
  int t = (int)((base >> 11) & (TDIM - 1));
  const float4* p = reinterpret_cast<const float4*>(Q + base);
  float4 v0 = p[0], v1 = p[1];
  float q[8] = {v0.x, v0.y, v0.z, v0.w, v1.x, v1.y, v1.z, v1.w};
  us r[8];
  float tf = (float)t;
#pragma unroll
  for (int pr = 0; pr < 4; ++pr) {
    int nn = n + pr * 2;
    float freq = __builtin_exp2f((float)nn * (-1.0f / 128.0f)) * 0.15915494309189535f;
    float ph = tf * freq;
    ph = ph - __builtin_floorf(ph);
    float c = __builtin_amdgcn_cosf(ph);
    float s = __builtin_amdgcn_sinf(ph);
    float e = q[2 * pr], o = q[2 * pr + 1];
    r[2 * pr]     = f2bf(e * c - o * s);
    r[2 * pr + 1] = f2bf(o * c + e * s);
  }
  union { us usv[8]; bf16x8 v; } pk;
#pragma unroll
  for (int i = 0; i < 8; ++i) pk.usv[i] = r[i];
  *reinterpret_cast<bf16x8*>(QR + base) = pk.v;
}

// ---------------- V-transpose tile core (64x64, 256 threads; stride 67 = 2-way banks) ----------------
static __device__ __forceinline__ void vtrans_tile(const float* __restrict__ Vp,
                                                   us* __restrict__ Tp,
                                                   float* __restrict__ tile,
                                                   int t0, int n0, int tid) {
  {
    const int tx4 = tid & 15, ty = tid >> 4;   // 16 float4 cols x 16 rows
#pragma unroll
    for (int i = 0; i < 4; ++i) {
      int row = ty + i * 16;
      float4 v = *reinterpret_cast<const float4*>(
          Vp + (long)(t0 + row) * NDIM + n0 + tx4 * 4);
      float* d = &tile[row * 67 + tx4 * 4];
      d[0] = v.x; d[1] = v.y; d[2] = v.z; d[3] = v.w;
    }
  }
  __syncthreads();
  {
    const int sx = tid & 15, sy = tid >> 4;    // 16 t-quads x 16 n-rows
#pragma unroll
    for (int j = 0; j < 4; ++j) {
      int n = sy * 4 + j;
      unsigned r0 = f2bf(tile[(sx * 4 + 0) * 67 + n]);
      unsigned r1 = f2bf(tile[(sx * 4 + 1) * 67 + n]);
      unsigned r2 = f2bf(tile[(sx * 4 + 2) * 67 + n]);
      unsigned r3 = f2bf(tile[(sx * 4 + 3) * 67 + n]);
      uint2 val;
      val.x = r0 | (r1 << 16);
      val.y = r2 | (r3 << 16);
      *reinterpret_cast<uint2*>(Tp + (long)(n0 + n) * TDIM + t0 + sx * 4) = val;
    }
  }
}

// ---------------- fused prep: rope + V-transpose + flag zeroing, ONE dispatch ----------------
// XCD-aligned: head = bid % nh for BOTH rope and vtrans blocks, matching the gemm's
// head<->XCD mapping -> freshly written QR/VT stays in the consuming XCD's L2.
__global__ __launch_bounds__(256) void prep_kernel(const float* __restrict__ Q,
                                                   const float* __restrict__ V,
                                                   us* __restrict__ QR,
                                                   us* __restrict__ VT,
                                                   us* __restrict__ Sflag,
                                                   int nh) {
  __shared__ float tile[64 * 67];
  const int bid = (int)blockIdx.x;
  const int tid = (int)threadIdx.x;
  const int nrope = nh * 2048;             // (nh*TN/8)/256 blocks
  const long TN8 = (long)TDIM * NDIM / 8;  // bf16x8 units per head
  if (bid == 0) {                          // parallel flag zeroing (40 per head)
    for (int k = tid; k < nh * 40; k += 256) {
      int h = k / 40, i = k % 40;
      unsigned* f = (unsigned*)(Sflag + (long)h * TDIM * LD + 1792);
      __hip_atomic_store(&f[i], 0u, __ATOMIC_RELAXED, __HIP_MEMORY_SCOPE_AGENT);
    }
  }
  if (bid < nrope) {
    const int h = bid % nh, j = bid / nh;  // bid%8 -> XCD h (fused path)
    rope_unit(Q, QR, (long)h * TN8 + (long)j * 256 + tid);
    return;
  }
  const int vb = bid - nrope;              // 0..nh*1024-1
  const int bh = vb % nh, rem = vb / nh;   // XCD-aligned head
  vtrans_tile(V + (long)bh * TDIM * NDIM, VT + (long)bh * TDIM * NDIM, tile,
              (rem & 31) * 64, (rem >> 5) * 64, tid);
}

// ---------------- shared 256x256 8-phase NT tile runner (BK=64, 8 waves) [r4/r8 verbatim] ----------------
template <int PASS>
__device__ __forceinline__ void run_tile(const us* __restrict__ A,
                                         const us* __restrict__ B,
                                         void* __restrict__ Cbase,
                                         us* __restrict__ lds,
                                         int rt, int ct, int tid,
                                         unsigned* __restrict__ fh) {
  const int lane = tid & 63, wid = tid >> 6;
  const int wr = wid >> 2, wc = wid & 3;          // 2 x 4 waves; wave tile 128 x 64
  const int l15 = lane & 15, l4 = lane >> 4;
  const int row0 = rt * 256, col0 = ct * 256;
  const int kts = (PASS == 0) ? 32 : (rt + 1) * 4;
  const int fbase = rt * (rt + 1) / 2;

  if constexpr (PASS == 1) {
    if (wid == 0) {
      unsigned need = (1u << (rt + 1)) - 1u;
      for (;;) {
        unsigned ok = 0;
        if (lane <= rt)
          ok = (__hip_atomic_fetch_add(&fh[fbase + lane], 0u, __ATOMIC_RELAXED,
                                       __HIP_MEMORY_SCOPE_AGENT) != 0u);
        unsigned long long m = __ballot(ok);
        if (((unsigned)m & need) == need) break;
        __builtin_amdgcn_s_sleep(8);
      }
    }
    __builtin_amdgcn_s_barrier();
    asm volatile("" ::: "memory");  // no stage-load hoisting above the gate
  }

  f32x4 acc[8][4];
#pragma unroll
  for (int m = 0; m < 8; ++m)
#pragma unroll
    for (int n = 0; n < 4; ++n) acc[m][n] = (f32x4){0.f, 0.f, 0.f, 0.f};

  auto stage = [&](int half /*0=A0,1=A1,2=B0,3=B1*/, int t) {
    const us* g0 = (half < 2) ? A : B;
    const int tr0 = (half < 2) ? row0 : col0;
    const int h = half & 1;
    us* lb = lds + ((half < 2) ? 0 : 32768) + (t & 1) * 16384;
    const int k0 = t * 64;
#pragma unroll
    for (int r = 0; r < 2; ++r) {
      int off = r * 512 + tid;          // 16B-unit index within the 16KB half
      int row = off >> 3;
      int ch = off & 7;
      int chl = ch ^ (row & 7);
      const us* g = g0 + (long)(tr0 + h * 128 + row) * LD + (k0 + chl * 8);
      us* l = lb + h * 8192 + off * 8;  // linear per-lane dest
      __builtin_amdgcn_global_load_lds(
          (const __attribute__((address_space(1))) unsigned int*)g,
          (__attribute__((address_space(3))) unsigned int*)l, 16, 0, 0);
    }
  };
  auto ldA = [&](int b, int m, int ks) -> bf16x8 {
    int row = wr * 128 + m * 16 + l15;
    int ch = (ks * 4 + l4) ^ (row & 7);
    return *reinterpret_cast<const bf16x8*>(lds + b * 16384 + row * 64 + ch * 8);
  };
  auto ldB = [&](int b, int n, int ks) -> bf16x8 {
    int row = wc * 64 + n * 16 + l15;
    int ch = (ks * 4 + l4) ^ (row & 7);
    return *reinterpret_cast<const bf16x8*>(lds + 32768 + b * 16384 + row * 64 + ch * 8);
  };

  // Prologue: tile0 fully, tile1 B-halves; wait tile0 landed (4 insts outstanding).
  stage(0, 0); stage(1, 0); stage(2, 0); stage(3, 0);
  if (1 < kts) { stage(2, 1); stage(3, 1); }
  asm volatile("s_waitcnt vmcnt(4)" ::: "memory");
  __builtin_amdgcn_s_barrier();
  __builtin_amdgcn_sched_barrier(0);

  bf16x8 af[4][2], bfr[4][2];
  for (int t = 0; t < kts; ++t) {
    const int b = t & 1;
    // ---- phase 1: read A m0-3 + B n0-1; stage A-half0(t+1); MFMA q(0,0) ----
#pragma unroll
    for (int m = 0; m < 4; ++m) { af[m][0] = ldA(b, m, 0); af[m][1] = ldA(b, m, 1); }
#pragma unroll
    for (int n = 0; n < 2; ++n) { bfr[n][0] = ldB(b, n, 0); bfr[n][1] = ldB(b, n, 1); }
    if (t + 1 < kts) stage(0, t + 1);
    __builtin_amdgcn_s_barrier();
    asm volatile("s_waitcnt lgkmcnt(0)" ::: "memory");
    __builtin_amdgcn_sched_barrier(0);
    __builtin_amdgcn_s_setprio(1);
#pragma unroll
    for (int m = 0; m < 4; ++m)
#pragma unroll
      for (int n = 0; n < 2; ++n)
#pragma unroll
        for (int ks = 0; ks < 2; ++ks)
          acc[m][n] = __builtin_amdgcn_mfma_f32_16x16x32_bf16(af[m][ks], bfr[n][ks], acc[m][n], 0, 0, 0);
    __builtin_amdgcn_s_setprio(0);
    __builtin_amdgcn_sched_barrier(0);
    __builtin_amdgcn_s_barrier();
    // ---- phase 2: read B n2-3; stage A-half1(t+1); MFMA q(0,1) ----
#pragma unroll
    for (int n = 2; n < 4; ++n) { bfr[n][0] = ldB(b, n, 0); bfr[n][1] = ldB(b, n, 1); }
    if (t + 1 < kts) stage(1, t + 1);
    __builtin_amdgcn_s_barrier();
    asm volatile("s_waitcnt lgkmcnt(0)" ::: "memory");
    __builtin_amdgcn_sched_barrier(0);
    __builtin_amdgcn_s_setprio(1);
#pragma unroll
    for (int m = 0; m < 4; ++m)
#pragma unroll
      for (int n = 2; n < 4; ++n)
#pragma unroll
        for (int ks = 0; ks < 2; ++ks)
          acc[m][n] = __builtin_amdgcn_mfma_f32_16x16x32_bf16(af[m][ks], bfr[n][ks], acc[m][n], 0, 0, 0);
    __builtin_amdgcn_s_setprio(0);
    __builtin_amdgcn_sched_barrier(0);
    __builtin_amdgcn_s_barrier();
    // ---- phase 3: read A m4-7; stage B-half0(t+2); MFMA q(1,0) ----
#pragma unroll
    for (int m = 0; m < 4; ++m) { af[m][0] = ldA(b, m + 4, 0); af[m][1] = ldA(b, m + 4, 1); }
    if (t + 2 < kts) stage(2, t + 2);
    __builtin_amdgcn_s_barrier();
    asm volatile("s_waitcnt lgkmcnt(0)" ::: "memory");
    __builtin_amdgcn_sched_barrier(0);
    __builtin_amdgcn_s_setprio(1);
#pragma unroll
    for (int m = 0; m < 4; ++m)
#pragma unroll
      for (int n = 0; n < 2; ++n)
#pragma unroll
        for (int ks = 0; ks < 2; ++ks)
          acc[m + 4][n] = __builtin_amdgcn_mfma_f32_16x16x32_bf16(af[m][ks], bfr[n][ks], acc[m + 4][n], 0, 0, 0);
    __builtin_amdgcn_s_setprio(0);
    __builtin_amdgcn_sched_barrier(0);
    __builtin_amdgcn_s_barrier();
    // ---- phase 4: stage B-half1(t+2); MFMA q(1,1); counted vmcnt; barrier ----
    if (t + 2 < kts) stage(3, t + 2);
    __builtin_amdgcn_s_setprio(1);
#pragma unroll
    for (int m = 0; m < 4; ++m)
#pragma unroll
      for (int n = 2; n < 4; ++n)
#pragma unroll
        for (int ks = 0; ks < 2; ++ks)
          acc[m + 4][n] = __builtin_amdgcn_mfma_f32_16x16x32_bf16(af[m][ks], bfr[n][ks], acc[m + 4][n], 0, 0, 0);
    __builtin_amdgcn_s_setprio(0);
    if (t + 2 < kts) { asm volatile("s_waitcnt vmcnt(4)" ::: "memory"); }  // tile t+1 landed; B(t+2) in flight
    else             { asm volatile("s_waitcnt vmcnt(0)" ::: "memory"); }  // tile drain
    __builtin_amdgcn_sched_barrier(0);
    __builtin_amdgcn_s_barrier();
    __builtin_amdgcn_sched_barrier(0);
  }

  // Epilogue. C/D layout: col=lane&15, row=(lane>>4)*4+j.
  if constexpr (PASS == 0) {
    us* C = (us*)Cbase;
    const bool diag = (rt == ct);
#pragma unroll
    for (int m = 0; m < 8; ++m) {
      int r0 = row0 + wr * 128 + m * 16 + l4 * 4;
#pragma unroll
      for (int n = 0; n < 4; ++n) {
        int cc = col0 + wc * 64 + n * 16 + l15;
#pragma unroll
        for (int j = 0; j < 4; ++j) {
          int tt = r0 + j;
          float v = acc[m][n][j];
          if (diag && cc >= tt) v = 0.0f;  // strict causal
          C[(long)tt * LD + cc] = f2bf(v);
        }
      }
    }
    __syncthreads();  // drain all S stores (vmcnt 0) before release
    if (tid == 0)
      __hip_atomic_store(&fh[fbase + ct], 1u, __ATOMIC_RELEASE,
                         __HIP_MEMORY_SCOPE_AGENT);  // wbl2 -> cross-XCD visible
  } else {
    float* C = (float*)Cbase;
#pragma unroll
    for (int m = 0; m < 8; ++m) {
      int r0 = row0 + wr * 128 + m * 16 + l4 * 4;
#pragma unroll
      for (int n = 0; n < 4; ++n) {
        int cc = col0 + wc * 64 + n * 16 + l15;
#pragma unroll
        for (int j = 0; j < 4; ++j)
          C[(long)(r0 + j) * LD + cc] = acc[m][n][j];
      }
    }
  }
}

// ---------------- fused persistent pass0+pass1 (cooperative, grid=256) [r4/r8 verbatim] ----------------
__global__ __launch_bounds__(512, 2) void gemm_fused(const us* __restrict__ QR,
                                                     const us* __restrict__ VT,
                                                     us* __restrict__ S,
                                                     float* __restrict__ Out) {
  extern __shared__ us lds[];
  const int b = (int)blockIdx.x;
  const int head = b & 7, u = b >> 3;   // b%8 -> XCD: one head per XCD L2
  const int tid = (int)threadIdx.x;
  const us* QRh = QR + (long)head * TDIM * LD;
  const us* VTh = VT + (long)head * TDIM * LD;
  us* Sh = S + (long)head * TDIM * LD;
  float* Oh = Out + (long)head * TDIM * LD;
  unsigned* fh = (unsigned*)(Sh + 1792);  // 36 flags + queue counter (idx 36)
  unsigned* qc = fh + 36;

  // ---- pass 0 (static; unconditional producer prefix: deadlock-free) ----
  int rt0, ct0;
  if (u < 8)       { rt0 = 7; ct0 = u; }
  else if (u < 15) { rt0 = 6; ct0 = u - 8; }
  else if (u < 21) { rt0 = 5; ct0 = u - 15; }
  else if (u < 26) { rt0 = 4; ct0 = u - 21; }
  else if (u < 30) { rt0 = 3; ct0 = u - 26; }
  else             { rt0 = 2; ct0 = (u == 30) ? 0 : 2; }
  run_tile<0>(QRh, QRh, Sh, lds, rt0, ct0, tid, fh);
  if (u >= 28) {  // second (light-band) tiles: ready ~64 kts, consumed ~64-72
    int rt1, ct1;
    if (u == 28)      { rt1 = 1; ct1 = 0; }
    else if (u == 29) { rt1 = 1; ct1 = 1; }
    else if (u == 30) { rt1 = 2; ct1 = 1; }
    else              { rt1 = 0; ct1 = 0; }
    run_tile<0>(QRh, QRh, Sh, lds, rt1, ct1, tid, fh);
    // static light pass-1 tile: 8 kts -> this block totals exactly 72 kts
    run_tile<1>(Sh, VTh, Oh, lds, 1, u - 28, tid, fh);
  }

  // ---- pass 1 (dynamic 60-tile queue, heavy-first) ----
  // i<48: bands 7..2 (rt=7-(i>>3), ct=i&7); i 48-51: (1, ct=4..7); i 52-59: (0, ct).
  for (;;) {
    if (tid == 0) {
      unsigned i = __hip_atomic_fetch_add(qc, 1u, __ATOMIC_RELAXED,
                                          __HIP_MEMORY_SCOPE_AGENT);
      *(volatile unsigned*)lds = i;
    }
    __syncthreads();
    unsigned i = *(volatile unsigned*)lds;
    __syncthreads();  // all read before prologue stages overwrite lds[0]
    if (i >= 60) break;
    int rt, ct;
    if (i < 48)      { rt = 7 - (int)(i >> 3); ct = (int)(i & 7); }
    else if (i < 52) { rt = 1; ct = (int)(i - 44); }
    else             { rt = 0; ct = (int)(i - 52); }
    run_tile<1>(Sh, VTh, Oh, lds, rt, ct, tid, fh);
  }
}

// ---------------- standalone 2-dispatch kernels (fallback paths) ----------------
template <int PASS>
__global__ __launch_bounds__(512, 2) void gemm256(
    const us* __restrict__ Abase, const us* __restrict__ Bbase,
    void* __restrict__ Cbase, int nh) {
  extern __shared__ us lds[];
  int bid = (int)blockIdx.x;
  int head, rt = 0, ct, cls = 0;
  if constexpr (PASS == 0) {
    head = bid % nh;
    int tri = bid / nh;
    rt = 0;
    while ((rt + 1) * (rt + 2) / 2 <= tri) ++rt;
    ct = tri - rt * (rt + 1) / 2;
  } else {
    head = bid % nh;
    int rem = bid / nh;
    ct = rem & 7;
    cls = rem >> 3;
  }
  const us* A = Abase + (long)head * TDIM * LD;
  const us* B = Bbase + (long)head * TDIM * LD;
  us* Sh = (us*)Cbase + (long)head * TDIM * LD;
  const int tid = (int)threadIdx.x;
  const int NSEG = (PASS == 0) ? 1 : 2;
#pragma unroll 1
  for (int seg = 0; seg < NSEG; ++seg) {
    int rts = rt, cts = ct;
    if constexpr (PASS == 1) { rts = seg ? cls : 7 - cls; cts = ct; }
    if constexpr (PASS == 0) {
      run_tile<0>(A, A, Sh, lds, rts, cts, tid, (unsigned*)(Sh + 1792));
    } else {
      float* Oh = (float*)Cbase + (long)head * TDIM * LD;
      // pass-0 dispatch fully precedes on-stream: all flags already 1
      run_tile<1>(A, B, Oh, lds, rts, cts, tid,
                  (unsigned*)((us*)Abase + (long)head * TDIM * LD + 1792));
    }
  }
}

extern "C" void kernel_launch(void* const* d_in, const int* in_sizes, int n_in,
                              void* d_out, int out_size, void* d_ws, size_t ws_size,
                              hipStream_t stream) {
  const float* Q = (const float*)d_in[0];
  const float* V = (const float*)d_in[1];
  float* Out = (float*)d_out;
  char* ws = (char*)d_ws;
  const long TN = (long)TDIM * NDIM;
  const size_t BUF = (size_t)BHN * TN * 2;   // 64 MiB
  const size_t PERBH = (size_t)TN * 2;       // 8 MiB
  const int SHMEM = 131072;                  // 128 KiB dynamic LDS

  hipFuncSetAttribute(reinterpret_cast<const void*>(&gemm_fused),
                      hipFuncAttributeMaxDynamicSharedMemorySize, SHMEM);
  hipFuncSetAttribute(reinterpret_cast<const void*>(&gemm256<0>),
                      hipFuncAttributeMaxDynamicSharedMemorySize, SHMEM);
  hipFuncSetAttribute(reinterpret_cast<const void*>(&gemm256<1>),
                      hipFuncAttributeMaxDynamicSharedMemorySize, SHMEM);

  if (ws_size >= 3 * BUF) {
    us* QRb = (us*)ws;
    us* VbT = (us*)(ws + BUF);
    us* S   = (us*)(ws + 2 * BUF);
    // one fused prep dispatch: nh*2048 rope blocks + nh*1024 vtrans blocks
    prep_kernel<<<dim3(BHN * 3072), dim3(256), 0, stream>>>(Q, V, QRb, VbT, S, BHN);
    void* args[] = {(void*)&QRb, (void*)&VbT, (void*)&S, (void*)&Out};
    hipError_t ce = hipLaunchCooperativeKernel(
        reinterpret_cast<const void*>(&gemm_fused), dim3(256), dim3(512),
        args, (unsigned)SHMEM, stream);
    if (ce != hipSuccess) {
      (void)hipGetLastError();
      // fallback: 2-dispatch path (pass0 completes before pass1 launches;
      // flags all released by then, so run_tile<1> gates succeed immediately)
      gemm256<0><<<dim3(36 * BHN), dim3(512), SHMEM, stream>>>(QRb, QRb, S, BHN);
      gemm256<1><<<dim3(32 * BHN), dim3(512), SHMEM, stream>>>(S, VbT, Out, BHN);
    }
  } else {
    // per-head fallback (min ~24 MiB ws)
    us* QR0 = (us*)ws;
    us* VT0 = (us*)(ws + PERBH);
    us* S0  = (us*)(ws + 2 * PERBH);
    for (int bh = 0; bh < BHN; ++bh) {
      prep_kernel<<<dim3(3072), dim3(256), 0, stream>>>(
          Q + bh * TN, V + bh * TN, QR0, VT0, S0, 1);
      gemm256<0><<<dim3(36), dim3(512), SHMEM, stream>>>(QR0, QR0, S0, 1);
      gemm256<1><<<dim3(32), dim3(512), SHMEM, stream>>>(S0, VT0, Out + bh * TN, 1);
    }
  }
}

// Round 10
// 256.238 us; speedup vs baseline: 1.0395x; 1.0395x over previous
//
#include <hip/hip_runtime.h>
#include <hip/hip_bf16.h>

#define TDIM 2048
#define NDIM 2048
#define BHN  8
#define LD   2048

typedef __attribute__((ext_vector_type(8))) short bf16x8;
typedef __attribute__((ext_vector_type(4))) float f32x4;
typedef unsigned short us;

static __device__ __forceinline__ us f2bf(float x) {
  union { __hip_bfloat16 h; us u; } cv;
  cv.h = __float2bfloat16(x);
  return cv.u;
}

// ---------------- RoPE core (one bf16x8 unit, flat index over heads) ----------------
static __device__ __forceinline__ void rope_unit(const float* __restrict__ Q,
                                                 us* __restrict__ QR, long idx) {
  long base = idx * 8;
  int n = (int)(base & (NDIM - 1));
  int t = (int)((base >> 11) & (TDIM - 1));
  const float4* p = reinterpret_cast<const float4*>(Q + base);
  float4 v0 = p[0], v1 = p[1];
  float q[8] = {v0.x, v0.y, v0.z, v0.w, v1.x, v1.y, v1.z, v1.w};
  us r[8];
  float tf = (float)t;
#pragma unroll
  for (int pr = 0; pr < 4; ++pr) {
    int nn = n + pr * 2;
    float freq = __builtin_exp2f((float)nn * (-1.0f / 128.0f)) * 0.15915494309189535f;
    float ph = tf * freq;
    ph = ph - __builtin_floorf(ph);
    float c = __builtin_amdgcn_cosf(ph);
    float s = __builtin_amdgcn_sinf(ph);
    float e = q[2 * pr], o = q[2 * pr + 1];
    r[2 * pr]     = f2bf(e * c - o * s);
    r[2 * pr + 1] = f2bf(o * c + e * s);
  }
  union { us usv[8]; bf16x8 v; } pk;
#pragma unroll
  for (int i = 0; i < 8; ++i) pk.usv[i] = r[i];
  *reinterpret_cast<bf16x8*>(QR + base) = pk.v;
}

// ---------------- V-transpose tile core (64x64, 256 threads) [r8 verbatim] ----------------
static __device__ __forceinline__ void vtrans_tile(const float* __restrict__ Vp,
                                                   us* __restrict__ Tp,
                                                   float* __restrict__ tile,
                                                   int t0, int n0, int tid) {
  {
    const int tx4 = tid & 15, ty = tid >> 4;   // 16 float4 cols x 16 rows
#pragma unroll
    for (int i = 0; i < 4; ++i) {
      int row = ty + i * 16;
      float4 v = *reinterpret_cast<const float4*>(
          Vp + (long)(t0 + row) * NDIM + n0 + tx4 * 4);
      float* d = &tile[row * 66 + tx4 * 4];
      d[0] = v.x; d[1] = v.y; d[2] = v.z; d[3] = v.w;
    }
  }
  __syncthreads();
  {
    const int sx = tid & 15, sy = tid >> 4;    // 16 t-quads x 16 n-rows
#pragma unroll
    for (int j = 0; j < 4; ++j) {
      int n = sy * 4 + j;
      unsigned r0 = f2bf(tile[(sx * 4 + 0) * 66 + n]);
      unsigned r1 = f2bf(tile[(sx * 4 + 1) * 66 + n]);
      unsigned r2 = f2bf(tile[(sx * 4 + 2) * 66 + n]);
      unsigned r3 = f2bf(tile[(sx * 4 + 3) * 66 + n]);
      uint2 val;
      val.x = r0 | (r1 << 16);
      val.y = r2 | (r3 << 16);
      *reinterpret_cast<uint2*>(Tp + (long)(n0 + n) * TDIM + t0 + sx * 4) = val;
    }
  }
}

// ---------------- fused prep: rope + V-transpose + flag zeroing, ONE dispatch ----------------
// [r8 verbatim, except flag zeroing parallelized across block 0's threads]
__global__ __launch_bounds__(256) void prep_kernel(const float* __restrict__ Q,
                                                   const float* __restrict__ V,
                                                   us* __restrict__ QR,
                                                   us* __restrict__ VT,
                                                   us* __restrict__ Sflag,
                                                   int nh) {
  __shared__ float tile[64 * 66];
  const int bid = (int)blockIdx.x;
  const int tid = (int)threadIdx.x;
  const int nrope = nh * 2048;             // (nh*TN/8)/256 blocks
  if (bid == 0) {                          // parallel flag zeroing (40 per head)
    for (int k = tid; k < nh * 40; k += 256) {
      int h = k / 40, i = k % 40;
      unsigned* f = (unsigned*)(Sflag + (long)h * TDIM * LD + 1792);
      __hip_atomic_store(&f[i], 0u, __ATOMIC_RELAXED, __HIP_MEMORY_SCOPE_AGENT);
    }
  }
  if (bid < nrope) {
    rope_unit(Q, QR, (long)bid * 256 + tid);
    return;
  }
  const int vb = bid - nrope;              // 0..nh*1024-1
  const int bh = vb >> 10;                 // 1024 blocks/head
  const int rem = vb & 1023;
  vtrans_tile(V + (long)bh * TDIM * NDIM, VT + (long)bh * TDIM * NDIM, tile,
              (rem & 31) * 64, (rem >> 5) * 64, tid);
}

// ---------------- shared 256x256 8-phase NT tile runner (BK=64, 8 waves) [r8 verbatim] ----------------
template <int PASS>
__device__ __forceinline__ void run_tile(const us* __restrict__ A,
                                         const us* __restrict__ B,
                                         void* __restrict__ Cbase,
                                         us* __restrict__ lds,
                                         int rt, int ct, int tid,
                                         unsigned* __restrict__ fh) {
  const int lane = tid & 63, wid = tid >> 6;
  const int wr = wid >> 2, wc = wid & 3;          // 2 x 4 waves; wave tile 128 x 64
  const int l15 = lane & 15, l4 = lane >> 4;
  const int row0 = rt * 256, col0 = ct * 256;
  const int kts = (PASS == 0) ? 32 : (rt + 1) * 4;
  const int fbase = rt * (rt + 1) / 2;

  if constexpr (PASS == 1) {
    if (wid == 0) {
      unsigned need = (1u << (rt + 1)) - 1u;
      for (;;) {
        unsigned ok = 0;
        if (lane <= rt)
          ok = (__hip_atomic_fetch_add(&fh[fbase + lane], 0u, __ATOMIC_RELAXED,
                                       __HIP_MEMORY_SCOPE_AGENT) != 0u);
        unsigned long long m = __ballot(ok);
        if (((unsigned)m & need) == need) break;
        __builtin_amdgcn_s_sleep(8);
      }
    }
    __builtin_amdgcn_s_barrier();
    asm volatile("" ::: "memory");  // no stage-load hoisting above the gate
  }

  f32x4 acc[8][4];
#pragma unroll
  for (int m = 0; m < 8; ++m)
#pragma unroll
    for (int n = 0; n < 4; ++n) acc[m][n] = (f32x4){0.f, 0.f, 0.f, 0.f};

  auto stage = [&](int half /*0=A0,1=A1,2=B0,3=B1*/, int t) {
    const us* g0 = (half < 2) ? A : B;
    const int tr0 = (half < 2) ? row0 : col0;
    const int h = half & 1;
    us* lb = lds + ((half < 2) ? 0 : 32768) + (t & 1) * 16384;
    const int k0 = t * 64;
#pragma unroll
    for (int r = 0; r < 2; ++r) {
      int off = r * 512 + tid;          // 16B-unit index within the 16KB half
      int row = off >> 3;
      int ch = off & 7;
      int chl = ch ^ (row & 7);
      const us* g = g0 + (long)(tr0 + h * 128 + row) * LD + (k0 + chl * 8);
      us* l = lb + h * 8192 + off * 8;  // linear per-lane dest
      __builtin_amdgcn_global_load_lds(
          (const __attribute__((address_space(1))) unsigned int*)g,
          (__attribute__((address_space(3))) unsigned int*)l, 16, 0, 0);
    }
  };
  auto ldA = [&](int b, int m, int ks) -> bf16x8 {
    int row = wr * 128 + m * 16 + l15;
    int ch = (ks * 4 + l4) ^ (row & 7);
    return *reinterpret_cast<const bf16x8*>(lds + b * 16384 + row * 64 + ch * 8);
  };
  auto ldB = [&](int b, int n, int ks) -> bf16x8 {
    int row = wc * 64 + n * 16 + l15;
    int ch = (ks * 4 + l4) ^ (row & 7);
    return *reinterpret_cast<const bf16x8*>(lds + 32768 + b * 16384 + row * 64 + ch * 8);
  };

  // Prologue: tile0 fully, tile1 B-halves; wait tile0 landed (4 insts outstanding).
  stage(0, 0); stage(1, 0); stage(2, 0); stage(3, 0);
  if (1 < kts) { stage(2, 1); stage(3, 1); }
  asm volatile("s_waitcnt vmcnt(4)" ::: "memory");
  __builtin_amdgcn_s_barrier();
  __builtin_amdgcn_sched_barrier(0);

  bf16x8 af[4][2], bfr[4][2];
  for (int t = 0; t < kts; ++t) {
    const int b = t & 1;
    // ---- phase 1: read A m0-3 + B n0-1; stage A-half0(t+1); MFMA q(0,0) ----
#pragma unroll
    for (int m = 0; m < 4; ++m) { af[m][0] = ldA(b, m, 0); af[m][1] = ldA(b, m, 1); }
#pragma unroll
    for (int n = 0; n < 2; ++n) { bfr[n][0] = ldB(b, n, 0); bfr[n][1] = ldB(b, n, 1); }
    if (t + 1 < kts) stage(0, t + 1);
    __builtin_amdgcn_s_barrier();
    asm volatile("s_waitcnt lgkmcnt(0)" ::: "memory");
    __builtin_amdgcn_sched_barrier(0);
    __builtin_amdgcn_s_setprio(1);
#pragma unroll
    for (int m = 0; m < 4; ++m)
#pragma unroll
      for (int n = 0; n < 2; ++n)
#pragma unroll
        for (int ks = 0; ks < 2; ++ks)
          acc[m][n] = __builtin_amdgcn_mfma_f32_16x16x32_bf16(af[m][ks], bfr[n][ks], acc[m][n], 0, 0, 0);
    __builtin_amdgcn_s_setprio(0);
    __builtin_amdgcn_sched_barrier(0);
    __builtin_amdgcn_s_barrier();
    // ---- phase 2: read B n2-3; stage A-half1(t+1); MFMA q(0,1) ----
#pragma unroll
    for (int n = 2; n < 4; ++n) { bfr[n][0] = ldB(b, n, 0); bfr[n][1] = ldB(b, n, 1); }
    if (t + 1 < kts) stage(1, t + 1);
    __builtin_amdgcn_s_barrier();
    asm volatile("s_waitcnt lgkmcnt(0)" ::: "memory");
    __builtin_amdgcn_sched_barrier(0);
    __builtin_amdgcn_s_setprio(1);
#pragma unroll
    for (int m = 0; m < 4; ++m)
#pragma unroll
      for (int n = 2; n < 4; ++n)
#pragma unroll
        for (int ks = 0; ks < 2; ++ks)
          acc[m][n] = __builtin_amdgcn_mfma_f32_16x16x32_bf16(af[m][ks], bfr[n][ks], acc[m][n], 0, 0, 0);
    __builtin_amdgcn_s_setprio(0);
    __builtin_amdgcn_sched_barrier(0);
    __builtin_amdgcn_s_barrier();
    // ---- phase 3: read A m4-7; stage B-half0(t+2); MFMA q(1,0) ----
#pragma unroll
    for (int m = 0; m < 4; ++m) { af[m][0] = ldA(b, m + 4, 0); af[m][1] = ldA(b, m + 4, 1); }
    if (t + 2 < kts) stage(2, t + 2);
    __builtin_amdgcn_s_barrier();
    asm volatile("s_waitcnt lgkmcnt(0)" ::: "memory");
    __builtin_amdgcn_sched_barrier(0);
    __builtin_amdgcn_s_setprio(1);
#pragma unroll
    for (int m = 0; m < 4; ++m)
#pragma unroll
      for (int n = 0; n < 2; ++n)
#pragma unroll
        for (int ks = 0; ks < 2; ++ks)
          acc[m + 4][n] = __builtin_amdgcn_mfma_f32_16x16x32_bf16(af[m][ks], bfr[n][ks], acc[m + 4][n], 0, 0, 0);
    __builtin_amdgcn_s_setprio(0);
    __builtin_amdgcn_sched_barrier(0);
    __builtin_amdgcn_s_barrier();
    // ---- phase 4: stage B-half1(t+2); MFMA q(1,1); counted vmcnt; barrier ----
    if (t + 2 < kts) stage(3, t + 2);
    __builtin_amdgcn_s_setprio(1);
#pragma unroll
    for (int m = 0; m < 4; ++m)
#pragma unroll
      for (int n = 2; n < 4; ++n)
#pragma unroll
        for (int ks = 0; ks < 2; ++ks)
          acc[m + 4][n] = __builtin_amdgcn_mfma_f32_16x16x32_bf16(af[m][ks], bfr[n][ks], acc[m + 4][n], 0, 0, 0);
    __builtin_amdgcn_s_setprio(0);
    if (t + 2 < kts) { asm volatile("s_waitcnt vmcnt(4)" ::: "memory"); }  // tile t+1 landed; B(t+2) in flight
    else             { asm volatile("s_waitcnt vmcnt(0)" ::: "memory"); }  // tile drain
    __builtin_amdgcn_sched_barrier(0);
    __builtin_amdgcn_s_barrier();
    __builtin_amdgcn_sched_barrier(0);
  }

  // Epilogue. C/D layout: col=lane&15, row=(lane>>4)*4+j.
  if constexpr (PASS == 0) {
    us* C = (us*)Cbase;
    const bool diag = (rt == ct);
#pragma unroll
    for (int m = 0; m < 8; ++m) {
      int r0 = row0 + wr * 128 + m * 16 + l4 * 4;
#pragma unroll
      for (int n = 0; n < 4; ++n) {
        int cc = col0 + wc * 64 + n * 16 + l15;
#pragma unroll
        for (int j = 0; j < 4; ++j) {
          int tt = r0 + j;
          float v = acc[m][n][j];
          if (diag && cc >= tt) v = 0.0f;  // strict causal
          C[(long)tt * LD + cc] = f2bf(v);
        }
      }
    }
    __syncthreads();  // drain all S stores (vmcnt 0) before release
    if (tid == 0)
      __hip_atomic_store(&fh[fbase + ct], 1u, __ATOMIC_RELEASE,
                         __HIP_MEMORY_SCOPE_AGENT);  // wbl2 -> cross-XCD visible
  } else {
    float* C = (float*)Cbase;
#pragma unroll
    for (int m = 0; m < 8; ++m) {
      int r0 = row0 + wr * 128 + m * 16 + l4 * 4;
#pragma unroll
      for (int n = 0; n < 4; ++n) {
        int cc = col0 + wc * 64 + n * 16 + l15;
#pragma unroll
        for (int j = 0; j < 4; ++j)
          C[(long)(r0 + j) * LD + cc] = acc[m][n][j];
      }
    }
  }
}

// ---------------- fused persistent pass0+pass1 (cooperative, grid=256) [r8 verbatim] ----------------
__global__ __launch_bounds__(512, 2) void gemm_fused(const us* __restrict__ QR,
                                                     const us* __restrict__ VT,
                                                     us* __restrict__ S,
                                                     float* __restrict__ Out) {
  extern __shared__ us lds[];
  const int b = (int)blockIdx.x;
  const int head = b & 7, u = b >> 3;   // b%8 -> XCD: one head per XCD L2
  const int tid = (int)threadIdx.x;
  const us* QRh = QR + (long)head * TDIM * LD;
  const us* VTh = VT + (long)head * TDIM * LD;
  us* Sh = S + (long)head * TDIM * LD;
  float* Oh = Out + (long)head * TDIM * LD;
  unsigned* fh = (unsigned*)(Sh + 1792);  // 36 flags + queue counter (idx 36)
  unsigned* qc = fh + 36;

  // ---- pass 0 (static; unconditional producer prefix: deadlock-free) ----
  int rt0, ct0;
  if (u < 8)       { rt0 = 7; ct0 = u; }
  else if (u < 15) { rt0 = 6; ct0 = u - 8; }
  else if (u < 21) { rt0 = 5; ct0 = u - 15; }
  else if (u < 26) { rt0 = 4; ct0 = u - 21; }
  else if (u < 30) { rt0 = 3; ct0 = u - 26; }
  else             { rt0 = 2; ct0 = (u == 30) ? 0 : 2; }
  run_tile<0>(QRh, QRh, Sh, lds, rt0, ct0, tid, fh);
  if (u >= 28) {  // second (light-band) tiles: ready ~64 kts, consumed ~64-72
    int rt1, ct1;
    if (u == 28)      { rt1 = 1; ct1 = 0; }
    else if (u == 29) { rt1 = 1; ct1 = 1; }
    else if (u == 30) { rt1 = 2; ct1 = 1; }
    else              { rt1 = 0; ct1 = 0; }
    run_tile<0>(QRh, QRh, Sh, lds, rt1, ct1, tid, fh);
    // static light pass-1 tile: 8 kts -> this block totals exactly 72 kts
    run_tile<1>(Sh, VTh, Oh, lds, 1, u - 28, tid, fh);
  }

  // ---- pass 1 (dynamic 60-tile queue, heavy-first) ----
  // i<48: bands 7..2 (rt=7-(i>>3), ct=i&7); i 48-51: (1, ct=4..7); i 52-59: (0, ct).
  for (;;) {
    if (tid == 0) {
      unsigned i = __hip_atomic_fetch_add(qc, 1u, __ATOMIC_RELAXED,
                                          __HIP_MEMORY_SCOPE_AGENT);
      *(volatile unsigned*)lds = i;
    }
    __syncthreads();
    unsigned i = *(volatile unsigned*)lds;
    __syncthreads();  // all read before prologue stages overwrite lds[0]
    if (i >= 60) break;
    int rt, ct;
    if (i < 48)      { rt = 7 - (int)(i >> 3); ct = (int)(i & 7); }
    else if (i < 52) { rt = 1; ct = (int)(i - 44); }
    else             { rt = 0; ct = (int)(i - 52); }
    run_tile<1>(Sh, VTh, Oh, lds, rt, ct, tid, fh);
  }
}

// ---------------- standalone 2-dispatch kernels (fallback paths) ----------------
template <int PASS>
__global__ __launch_bounds__(512, 2) void gemm256(
    const us* __restrict__ Abase, const us* __restrict__ Bbase,
    void* __restrict__ Cbase, int nh) {
  extern __shared__ us lds[];
  int bid = (int)blockIdx.x;
  int head, rt = 0, ct, cls = 0;
  if constexpr (PASS == 0) {
    head = bid % nh;
    int tri = bid / nh;
    rt = 0;
    while ((rt + 1) * (rt + 2) / 2 <= tri) ++rt;
    ct = tri - rt * (rt + 1) / 2;
  } else {
    head = bid % nh;
    int rem = bid / nh;
    ct = rem & 7;
    cls = rem >> 3;
  }
  const us* A = Abase + (long)head * TDIM * LD;
  const us* B = Bbase + (long)head * TDIM * LD;
  us* Sh = (us*)Cbase + (long)head * TDIM * LD;
  const int tid = (int)threadIdx.x;
  const int NSEG = (PASS == 0) ? 1 : 2;
#pragma unroll 1
  for (int seg = 0; seg < NSEG; ++seg) {
    int rts = rt, cts = ct;
    if constexpr (PASS == 1) { rts = seg ? cls : 7 - cls; cts = ct; }
    if constexpr (PASS == 0) {
      run_tile<0>(A, A, Sh, lds, rts, cts, tid, (unsigned*)(Sh + 1792));
    } else {
      float* Oh = (float*)Cbase + (long)head * TDIM * LD;
      // pass-0 dispatch fully precedes on-stream: all flags already 1
      run_tile<1>(A, B, Oh, lds, rts, cts, tid,
                  (unsigned*)((us*)Abase + (long)head * TDIM * LD + 1792));
    }
  }
}

extern "C" void kernel_launch(void* const* d_in, const int* in_sizes, int n_in,
                              void* d_out, int out_size, void* d_ws, size_t ws_size,
                              hipStream_t stream) {
  const float* Q = (const float*)d_in[0];
  const float* V = (const float*)d_in[1];
  float* Out = (float*)d_out;
  char* ws = (char*)d_ws;
  const long TN = (long)TDIM * NDIM;
  const size_t BUF = (size_t)BHN * TN * 2;   // 64 MiB
  const size_t PERBH = (size_t)TN * 2;       // 8 MiB
  const int SHMEM = 131072;                  // 128 KiB dynamic LDS

  hipFuncSetAttribute(reinterpret_cast<const void*>(&gemm_fused),
                      hipFuncAttributeMaxDynamicSharedMemorySize, SHMEM);
  hipFuncSetAttribute(reinterpret_cast<const void*>(&gemm256<0>),
                      hipFuncAttributeMaxDynamicSharedMemorySize, SHMEM);
  hipFuncSetAttribute(reinterpret_cast<const void*>(&gemm256<1>),
                      hipFuncAttributeMaxDynamicSharedMemorySize, SHMEM);

  if (ws_size >= 3 * BUF) {
    us* QRb = (us*)ws;
    us* VbT = (us*)(ws + BUF);
    us* S   = (us*)(ws + 2 * BUF);
    // one fused prep dispatch: nh*2048 rope blocks + nh*1024 vtrans blocks
    prep_kernel<<<dim3(BHN * 3072), dim3(256), 0, stream>>>(Q, V, QRb, VbT, S, BHN);
    void* args[] = {(void*)&QRb, (void*)&VbT, (void*)&S, (void*)&Out};
    hipError_t ce = hipLaunchCooperativeKernel(
        reinterpret_cast<const void*>(&gemm_fused), dim3(256), dim3(512),
        args, (unsigned)SHMEM, stream);
    if (ce != hipSuccess) {
      (void)hipGetLastError();
      // fallback: 2-dispatch path (pass0 completes before pass1 launches;
      // flags all released by then, so run_tile<1> gates succeed immediately)
      gemm256<0><<<dim3(36 * BHN), dim3(512), SHMEM, stream>>>(QRb, QRb, S, BHN);
      gemm256<1><<<dim3(32 * BHN), dim3(512), SHMEM, stream>>>(S, VbT, Out, BHN);
    }
  } else {
    // per-head fallback (min ~24 MiB ws)
    us* QR0 = (us*)ws;
    us* VT0 = (us*)(ws + PERBH);
    us* S0  = (us*)(ws + 2 * PERBH);
    for (int bh = 0; bh < BHN; ++bh) {
      prep_kernel<<<dim3(3072), dim3(256), 0, stream>>>(
          Q + bh * TN, V + bh * TN, QR0, VT0, S0, 1);
      gemm256<0><<<dim3(36), dim3(512), SHMEM, stream>>>(QR0, QR0, S0, 1);
      gemm256<1><<<dim3(32), dim3(512), SHMEM, stream>>>(S0, VT0, Out + bh * TN, 1);
    }
  }
}